// Round 17
// baseline (397.432 us; speedup 1.0000x reference)
//
#include <hip/hip_runtime.h>
#include <hip/hip_bf16.h>
#include <cstdint>

#define NEGV (-10000.0f)

typedef short bf16x8 __attribute__((ext_vector_type(8)));
typedef short bf16x4 __attribute__((ext_vector_type(4)));
typedef float f32x4 __attribute__((ext_vector_type(4)));

__device__ __forceinline__ short f2bf(float f) {
  union { float f; uint32_t u; } v; v.f = f;
  uint32_t u = v.u + 0x7fffu + ((v.u >> 16) & 1u);
  return (short)(u >> 16);
}
__device__ __forceinline__ float b2f(short s) {
  union { uint32_t u; float f; } v; v.u = ((uint32_t)(uint16_t)s) << 16;
  return v.f;
}
__device__ __forceinline__ uint32_t pk2(float lo, float hi) {
  union { __hip_bfloat162 h2; uint32_t u; } cv;
  cv.h2.x = __float2bfloat16(lo);
  cv.h2.y = __float2bfloat16(hi);
  return cv.u;
}

// ---------------- P1: Wcat = [W1b-W1c | W1d] bf16 (256x256) + W2 bf16 ----------
__global__ void prep_weights(const float* __restrict__ W1, const float* __restrict__ W2,
                             short* __restrict__ Wcat, short* __restrict__ W2b) {
  int idx = blockIdx.x * 256 + threadIdx.x;
  if (idx < 65536) {
    int h = idx >> 8, k = idx & 255;
    float v = (k < 128) ? (W1[h * 512 + 128 + k] - W1[h * 512 + 256 + k])
                        : W1[h * 512 + 384 + (k - 128)];
    Wcat[idx] = f2bf(v);
  } else {
    int i = idx - 65536;
    W2b[i] = f2bf(W2[i]);
  }
}

// ---------------- P2: U[b][h] = b1[h] + sum_d (W1a+W1c)[h][d] * q[b][d] ----
__global__ void prep_u(const float* __restrict__ query, const float* __restrict__ W1,
                       const float* __restrict__ b1, float* __restrict__ U) {
  __shared__ float q8[8][128];
  int tid = threadIdx.x;
  int b0 = blockIdx.x * 8;
  for (int i = tid; i < 1024; i += 256)
    q8[i >> 7][i & 127] = query[(size_t)(b0 + (i >> 7)) * 128 + (i & 127)];
  __syncthreads();
  int h = tid;
  const float4* w0 = (const float4*)(W1 + (size_t)h * 512);
  const float4* w1 = (const float4*)(W1 + (size_t)h * 512 + 256);
  float acc[8];
  float bb = b1[h];
#pragma unroll
  for (int i = 0; i < 8; ++i) acc[i] = bb;
  for (int d4 = 0; d4 < 32; ++d4) {
    float4 wa = w0[d4], wb = w1[d4];
    float wv0 = wa.x + wb.x, wv1 = wa.y + wb.y, wv2 = wa.z + wb.z, wv3 = wa.w + wb.w;
#pragma unroll
    for (int i = 0; i < 8; ++i) {
      float4 qv = ((const float4*)q8[i])[d4];
      acc[i] += wv0 * qv.x + wv1 * qv.y + wv2 * qv.z + wv3 * qv.w;
    }
  }
#pragma unroll
  for (int i = 0; i < 8; ++i) U[(size_t)(b0 + i) * 256 + h] = acc[i];
}

// ---------------- K2: FLAT fused scores. Block = 64 rows of BL=409600. --------
// H1[bl,h] = PReLU(U[b(bl)] + Wcat·[k ; q(b)*k]); h2 = PReLU(W2·h1 + b2);
// scores = h2·W3. Standard tall-skinny GEMM pair, fused via 32 KB H1 LDS.
// 3 barriers/block, no phase lockstep; Wcat/W2 stream from L2 (192 KB, shared).
__global__ __launch_bounds__(256, 2) void din_scores_flat(
    const float* __restrict__ query, const float* __restrict__ keys,
    const float* __restrict__ b2p, const float* __restrict__ a1p,
    const float* __restrict__ a2p, const float* __restrict__ W3,
    const float* __restrict__ U, const short* __restrict__ Wcat,
    const short* __restrict__ W2b, float* __restrict__ scores_g) {
  __shared__ short H1t[64 * 256];    // 32 KB, XOR-swizzled rows
  __shared__ float U2[2][256];
  __shared__ float q2[2][128];
  __shared__ float b2l[128];
  __shared__ float w3l[128];
  __shared__ float wred[4][64];

  const int tid = threadIdx.x;
  const int lane = tid & 63, wid = tid >> 6;  // 4 waves
  const int lr = lane & 15, lg = lane >> 4;
  const int R0 = blockIdx.x * 64;
  const int b0 = R0 / 200;
  const int bs = (b0 + 1) * 200;              // first row of next b
  const int b1i = (b0 + 1 < 2048) ? (b0 + 1) : 2047;
  const float a1 = a1p[0], a2 = a2p[0];

  // ---- stage per-block constants ----
  for (int i = tid; i < 512; i += 256)
    U2[i >> 8][i & 255] = U[(size_t)((i < 256) ? b0 : b1i) * 256 + (i & 255)];
  if (tid < 256) q2[tid >> 7][tid & 127] = query[(size_t)((tid < 128) ? b0 : b1i) * 128 + (tid & 127)];
  if (tid < 128) { b2l[tid] = b2p[tid]; w3l[tid] = W3[tid]; }
  __syncthreads();

  // per-mt row info (row = R0 + mt*16 + lr for this lane)
  const float* kb[4];
  const float* qrow[4];
  int bi[4];
#pragma unroll
  for (int mt = 0; mt < 4; ++mt) {
    int grow = R0 + mt * 16 + lr;
    bi[mt] = (grow >= bs) ? 1 : 0;
    kb[mt] = keys + (size_t)grow * 128;
    qrow[mt] = q2[bi[mt]];
  }

  // ---- GEMM1: D[h][row] = Wcat · Y^T, K=256; wave owns 64 h (nt=0..3) ----
  f32x4 acc[4][4];  // [nt][mt], init with U bias
#pragma unroll
  for (int nt = 0; nt < 4; ++nt) {
    int h0 = wid * 64 + nt * 16 + lg * 4;
#pragma unroll
    for (int mt = 0; mt < 4; ++mt) {
      float4 uu = *(const float4*)(&U2[bi[mt]][h0]);
      acc[nt][mt][0] = uu.x; acc[nt][mt][1] = uu.y;
      acc[nt][mt][2] = uu.z; acc[nt][mt][3] = uu.w;
    }
  }

  // ks = 0..3: Y = keys (plain)
#pragma unroll
  for (int ks = 0; ks < 4; ++ks) {
    const int kk = ks * 32 + lg * 8;
    bf16x8 yf[4];
#pragma unroll
    for (int mt = 0; mt < 4; ++mt) {
      float4 x0 = *(const float4*)(kb[mt] + kk);
      float4 x1 = *(const float4*)(kb[mt] + kk + 4);
      union { bf16x8 v; uint32_t u[4]; } w;
      w.u[0] = pk2(x0.x, x0.y); w.u[1] = pk2(x0.z, x0.w);
      w.u[2] = pk2(x1.x, x1.y); w.u[3] = pk2(x1.z, x1.w);
      yf[mt] = w.v;
    }
#pragma unroll
    for (int nt = 0; nt < 4; ++nt) {
      int h = wid * 64 + nt * 16 + lr;
      bf16x8 wf = *(const bf16x8*)(Wcat + h * 256 + kk);
#pragma unroll
      for (int mt = 0; mt < 4; ++mt)
        acc[nt][mt] = __builtin_amdgcn_mfma_f32_16x16x32_bf16(wf, yf[mt], acc[nt][mt], 0, 0, 0);
    }
  }
  // ks = 4..7: Y = q (x) keys
#pragma unroll
  for (int ks = 4; ks < 8; ++ks) {
    const int kk = ks * 32 + lg * 8;
    const int d0 = kk - 128;
    bf16x8 yf[4];
#pragma unroll
    for (int mt = 0; mt < 4; ++mt) {
      float4 x0 = *(const float4*)(kb[mt] + d0);
      float4 x1 = *(const float4*)(kb[mt] + d0 + 4);
      float4 qa = *(const float4*)(qrow[mt] + d0);
      float4 qb = *(const float4*)(qrow[mt] + d0 + 4);
      union { bf16x8 v; uint32_t u[4]; } w;
      w.u[0] = pk2(x0.x * qa.x, x0.y * qa.y);
      w.u[1] = pk2(x0.z * qa.z, x0.w * qa.w);
      w.u[2] = pk2(x1.x * qb.x, x1.y * qb.y);
      w.u[3] = pk2(x1.z * qb.z, x1.w * qb.w);
      yf[mt] = w.v;
    }
#pragma unroll
    for (int nt = 0; nt < 4; ++nt) {
      int h = wid * 64 + nt * 16 + lr;
      bf16x8 wf = *(const bf16x8*)(Wcat + h * 256 + kk);
#pragma unroll
      for (int mt = 0; mt < 4; ++mt)
        acc[nt][mt] = __builtin_amdgcn_mfma_f32_16x16x32_bf16(wf, yf[mt], acc[nt][mt], 0, 0, 0);
    }
  }

  // epilogue1: PReLU(a1) -> H1t[row][h] (bf16x4 packed, XOR-swizzled)
#pragma unroll
  for (int nt = 0; nt < 4; ++nt) {
    int h0 = wid * 64 + nt * 16 + lg * 4;
#pragma unroll
    for (int mt = 0; mt < 4; ++mt) {
      int row = mt * 16 + lr;
      float v0 = acc[nt][mt][0], v1 = acc[nt][mt][1], v2 = acc[nt][mt][2], v3 = acc[nt][mt][3];
      v0 = (v0 >= 0.f) ? v0 : a1 * v0;
      v1 = (v1 >= 0.f) ? v1 : a1 * v1;
      v2 = (v2 >= 0.f) ? v2 : a1 * v2;
      v3 = (v3 >= 0.f) ? v3 : a1 * v3;
      union { bf16x4 v; uint32_t u[2]; } hh;
      hh.u[0] = pk2(v0, v1); hh.u[1] = pk2(v2, v3);
      *(bf16x4*)(&H1t[row * 256 + (h0 ^ ((row & 7) << 3))]) = hh.v;
    }
  }
  __syncthreads();

  // ---- GEMM2: D[g][row] = W2 · H1^T, K=256; wave owns 32 g (nt2=0..1) ----
  f32x4 acc2[2][4];
#pragma unroll
  for (int nt2 = 0; nt2 < 2; ++nt2) {
    int g0 = wid * 32 + nt2 * 16 + lg * 4;
#pragma unroll
    for (int mt = 0; mt < 4; ++mt) {
      acc2[nt2][mt][0] = b2l[g0]; acc2[nt2][mt][1] = b2l[g0 + 1];
      acc2[nt2][mt][2] = b2l[g0 + 2]; acc2[nt2][mt][3] = b2l[g0 + 3];
    }
  }
#pragma unroll
  for (int ks = 0; ks < 8; ++ks) {
    const int kk = ks * 32 + lg * 8;
    bf16x8 hf[4];
#pragma unroll
    for (int mt = 0; mt < 4; ++mt) {
      int row = mt * 16 + lr;
      hf[mt] = *(const bf16x8*)(&H1t[row * 256 + (kk ^ ((row & 7) << 3))]);
    }
#pragma unroll
    for (int nt2 = 0; nt2 < 2; ++nt2) {
      int g = wid * 32 + nt2 * 16 + lr;
      bf16x8 wf = *(const bf16x8*)(W2b + g * 256 + kk);
#pragma unroll
      for (int mt = 0; mt < 4; ++mt)
        acc2[nt2][mt] = __builtin_amdgcn_mfma_f32_16x16x32_bf16(wf, hf[mt], acc2[nt2][mt], 0, 0, 0);
    }
  }

  // epilogue2: PReLU(a2), dot W3, reduce over g
#pragma unroll
  for (int mt = 0; mt < 4; ++mt) {
    float s = 0.f;
#pragma unroll
    for (int nt2 = 0; nt2 < 2; ++nt2) {
      int g0 = wid * 32 + nt2 * 16 + lg * 4;
#pragma unroll
      for (int r = 0; r < 4; ++r) {
        float v = acc2[nt2][mt][r];
        v = (v >= 0.f) ? v : a2 * v;
        s += v * w3l[g0 + r];
      }
    }
    s += __shfl_xor(s, 16);
    s += __shfl_xor(s, 32);
    if (lg == 0) wred[wid][mt * 16 + lr] = s;
  }
  __syncthreads();

  if (tid < 64)
    scores_g[R0 + tid] = wred[0][tid] + wred[1][tid] + wred[2][tid] + wred[3][tid];
}

// ---------------- K3: masked softmax + weighted sum (streaming, R7) ----------
__global__ __launch_bounds__(256) void din_wsum(
    const float* __restrict__ keys, const int* __restrict__ mask,
    const float* __restrict__ scores_g, float* __restrict__ out) {
  __shared__ float wl[208];
  __shared__ float red[8];
  __shared__ float opart[8][128];

  const int tid = threadIdx.x;
  const int b = blockIdx.x;
  const int lane = tid & 63, wid = tid >> 6;

  float val = NEGV;
  int mk = 0;
  if (tid < 200) {
    mk = mask[(size_t)b * 200 + tid];
    val = mk ? scores_g[(size_t)b * 200 + tid] : NEGV;
  }
  float m = val;
#pragma unroll
  for (int off = 1; off < 64; off <<= 1) m = fmaxf(m, __shfl_xor(m, off));
  if (lane == 0) red[wid] = m;
  __syncthreads();
  float smax = fmaxf(fmaxf(red[0], red[1]), fmaxf(red[2], red[3]));
  float pex = (tid < 200 && mk) ? __expf(val - smax) : 0.f;
  float s = pex;
#pragma unroll
  for (int off = 1; off < 64; off <<= 1) s += __shfl_xor(s, off);
  if (lane == 0) red[4 + wid] = s;
  __syncthreads();
  float ssum = red[4] + red[5] + red[6] + red[7];
  float winv = (ssum > 0.f) ? 1.f / ssum : 0.f;
  if (tid < 208) wl[tid] = (tid < 200) ? pex * winv : 0.f;
  __syncthreads();

  {
    const int d4 = (tid & 31) << 2;
    const int slice = tid >> 5;
    float ax = 0.f, ay = 0.f, az = 0.f, aw = 0.f;
    for (int l = slice; l < 200; l += 8) {
      float wv = wl[l];
      float4 kv = *(const float4*)(keys + ((size_t)b * 200 + l) * 128 + d4);
      ax += wv * kv.x; ay += wv * kv.y; az += wv * kv.z; aw += wv * kv.w;
    }
    *(float4*)(&opart[slice][d4]) = make_float4(ax, ay, az, aw);
  }
  __syncthreads();
  if (tid < 128) {
    float acc = 0.f;
#pragma unroll
    for (int i = 0; i < 8; ++i) acc += opart[i][tid];
    out[(size_t)b * 128 + tid] = acc;
  }
}

extern "C" void kernel_launch(void* const* d_in, const int* in_sizes, int n_in,
                              void* d_out, int out_size, void* d_ws, size_t ws_size,
                              hipStream_t stream) {
  const float* query = (const float*)d_in[0];
  const float* keys  = (const float*)d_in[1];
  const int*   maskp = (const int*)d_in[2];
  const float* W1    = (const float*)d_in[3];
  const float* b1    = (const float*)d_in[4];
  const float* a1    = (const float*)d_in[5];
  const float* W2    = (const float*)d_in[6];
  const float* b2    = (const float*)d_in[7];
  const float* a2    = (const float*)d_in[8];
  const float* W3    = (const float*)d_in[9];
  float* out = (float*)d_out;

  // workspace layout
  float* U        = (float*)d_ws;                              // 2 MiB
  short* Wcat     = (short*)((char*)d_ws + 2097152);           // 128 KiB
  short* W2b      = Wcat + 65536;                              // 64 KiB
  float* scores_g = (float*)((char*)d_ws + 2097152 + 196608);  // 1.6 MiB

  prep_weights<<<384, 256, 0, stream>>>(W1, W2, Wcat, W2b);
  prep_u<<<256, 256, 0, stream>>>(query, W1, b1, U);
  din_scores_flat<<<6400, 256, 0, stream>>>(query, keys, b2, a1, a2, W3,
                                            U, Wcat, W2b, scores_g);
  din_wsum<<<2048, 256, 0, stream>>>(keys, maskp, scores_g, out);
}

// Round 18
// 143.275 us; speedup vs baseline: 2.7739x; 2.7739x over previous
//
#include <hip/hip_runtime.h>
#include <hip/hip_bf16.h>
#include <cstdint>

#define NEGV (-10000.0f)

typedef short bf16x8 __attribute__((ext_vector_type(8)));
typedef short bf16x4 __attribute__((ext_vector_type(4)));
typedef float f32x4 __attribute__((ext_vector_type(4)));

__device__ __forceinline__ short f2bf(float f) {
  union { float f; uint32_t u; } v; v.f = f;
  uint32_t u = v.u + 0x7fffu + ((v.u >> 16) & 1u);
  return (short)(u >> 16);
}
__device__ __forceinline__ float b2f(short s) {
  union { uint32_t u; float f; } v; v.u = ((uint32_t)(uint16_t)s) << 16;
  return v.f;
}
__device__ __forceinline__ uint32_t pk2(float lo, float hi) {
  union { __hip_bfloat162 h2; uint32_t u; } cv;
  cv.h2.x = __float2bfloat16(lo);
  cv.h2.y = __float2bfloat16(hi);
  return cv.u;
}

// LDS-only barrier: no vmcnt drain; ring prefetch loads survive barriers.
__device__ __forceinline__ void bar() {
  __builtin_amdgcn_sched_barrier(0);
  asm volatile("s_waitcnt lgkmcnt(0)" ::: "memory");
  __builtin_amdgcn_s_barrier();
  __builtin_amdgcn_sched_barrier(0);
}

// ---------------- P: merged prep. Blocks 0..383: weight combine; 384..639: U ----
__global__ __launch_bounds__(256) void prep_all(
    const float* __restrict__ query, const float* __restrict__ W1,
    const float* __restrict__ W2, const float* __restrict__ b1,
    short* __restrict__ Wk, short* __restrict__ Wd, short* __restrict__ W2b,
    float* __restrict__ U) {
  const int bid = blockIdx.x;
  const int tid = threadIdx.x;
  if (bid < 384) {
    int idx = bid * 256 + tid;
    if (idx < 32768) {
      int h = idx >> 7, d = idx & 127;
      Wk[idx] = f2bf(W1[h * 512 + 128 + d] - W1[h * 512 + 256 + d]);
    } else if (idx < 65536) {
      int i = idx - 32768;
      int h = i >> 7, d = i & 127;
      Wd[i] = f2bf(W1[h * 512 + 384 + d]);
    } else {
      int i = idx - 65536;
      W2b[i] = f2bf(W2[i]);
    }
    return;
  }
  // ---- U[b][h] = b1[h] + sum_d (W1a+W1c)[h][d] * q[b][d], 8 b per block ----
  __shared__ float q8[8][128];
  int b0 = (bid - 384) * 8;
  for (int i = tid; i < 1024; i += 256)
    q8[i >> 7][i & 127] = query[(size_t)(b0 + (i >> 7)) * 128 + (i & 127)];
  __syncthreads();
  int h = tid;
  const float4* w0 = (const float4*)(W1 + (size_t)h * 512);
  const float4* w1 = (const float4*)(W1 + (size_t)h * 512 + 256);
  float acc[8];
  float bb = b1[h];
#pragma unroll
  for (int i = 0; i < 8; ++i) acc[i] = bb;
  for (int d4 = 0; d4 < 32; ++d4) {
    float4 wa = w0[d4], wb = w1[d4];
    float wv0 = wa.x + wb.x, wv1 = wa.y + wb.y, wv2 = wa.z + wb.z, wv3 = wa.w + wb.w;
#pragma unroll
    for (int i = 0; i < 8; ++i) {
      float4 qv = ((const float4*)q8[i])[d4];
      acc[i] += wv0 * qv.x + wv1 * qv.y + wv2 * qv.z + wv3 * qv.w;
    }
  }
#pragma unroll
  for (int i = 0; i < 8; ++i) U[(size_t)(b0 + i) * 256 + h] = acc[i];
}

// ---------------- fused main: block = b, 4 waves, 16-l tiles, pipelined ------
// R14 verbatim (best measured: 147.9 us total). GEMM2(t-1) and GEMM1(t) in the
// SAME phase (different LDS buffers) -> 32 MFMA/wave/phase, ONE barrier/tile.
__global__ __launch_bounds__(256, 2) void din_fused(
    const float* __restrict__ query, const float* __restrict__ keys,
    const int* __restrict__ mask,
    const float* __restrict__ b2p, const float* __restrict__ a1p,
    const float* __restrict__ a2p, const float* __restrict__ W3,
    const float* __restrict__ U, const short* __restrict__ Wk,
    const short* __restrict__ Wd, const short* __restrict__ W2b,
    float* __restrict__ out) {
  __shared__ short Kt[2][16 * 128];   // 8 KB streaming key tiles, XOR-swizzled
  __shared__ short H1[2][16 * 256];   // 16 KB h1 tiles, XOR-swizzled
  __shared__ float wred[4][208];      // per-wave score partials
  __shared__ float Ul[256];
  __shared__ float b2l[128];
  __shared__ float w3l[128];
  __shared__ float wl[208];
  __shared__ float red[8];
  __shared__ float opart[8][128];

  const int tid = threadIdx.x;
  const int b = blockIdx.x;
  const int lane = tid & 63, wid = tid >> 6;  // 4 waves
  const int lr = lane & 15, lg = lane >> 4;

  const float a1 = a1p[0], a2 = a2p[0];

  Ul[tid] = U[(size_t)b * 256 + tid];
  if (tid < 128) { b2l[tid] = b2p[tid]; w3l[tid] = W3[tid]; }

  // ---- persistent fragments ----
  bf16x8 mf[4][4];   // GEMM1 A: M_b, wave owns 64 h
  {
    const float* qrow = query + (size_t)b * 128;
#pragma unroll
    for (int nt = 0; nt < 4; ++nt) {
      int h = wid * 64 + nt * 16 + lr;
#pragma unroll
      for (int ks = 0; ks < 4; ++ks) {
        int d0 = ks * 32 + lg * 8;
        bf16x8 wk = *(const bf16x8*)(Wk + h * 128 + d0);
        bf16x8 wd = *(const bf16x8*)(Wd + h * 128 + d0);
        float4 q0 = *(const float4*)(qrow + d0);
        float4 q1 = *(const float4*)(qrow + d0 + 4);
        float qv[8] = {q0.x, q0.y, q0.z, q0.w, q1.x, q1.y, q1.z, q1.w};
        float mv[8];
#pragma unroll
        for (int j = 0; j < 8; ++j) mv[j] = b2f(wk[j]) + b2f(wd[j]) * qv[j];
        union { bf16x8 v; uint32_t u[4]; } mm;
#pragma unroll
        for (int j = 0; j < 4; ++j) mm.u[j] = pk2(mv[2 * j], mv[2 * j + 1]);
        mf[nt][ks] = mm.v;
      }
    }
  }
  bf16x8 w2f[2][8];  // GEMM2 A: W2, wave owns 32 g
#pragma unroll
  for (int nt2 = 0; nt2 < 2; ++nt2) {
    int g = wid * 32 + nt2 * 16 + lr;
#pragma unroll
    for (int ks = 0; ks < 8; ++ks)
      w2f[nt2][ks] = *(const bf16x8*)(W2b + g * 256 + ks * 32 + lg * 8);
  }

  // staging geometry: 16 thr/row, 8 f32 (32B) per thread
  const int srow = tid >> 4;          // 0..15
  const int scol = (tid & 15) * 8;    // 0..120
  const int ssw = (srow & 7) << 3;

  float4 h0a, h0b;                    // ring hold: tile t+1
  {
    const float4* kp4 = (const float4*)(keys + ((size_t)b * 200 + srow) * 128 + scol);
    float4 s0 = kp4[0], s1 = kp4[1];
    union { bf16x8 v; uint32_t u[4]; } w;
    w.u[0] = pk2(s0.x, s0.y); w.u[1] = pk2(s0.z, s0.w);
    w.u[2] = pk2(s1.x, s1.y); w.u[3] = pk2(s1.z, s1.w);
    *(bf16x8*)(&Kt[0][srow * 128 + (scol ^ ssw)]) = w.v;
    const float4* kp4b = (const float4*)(keys + ((size_t)b * 200 + 16 + srow) * 128 + scol);
    h0a = kp4b[0]; h0b = kp4b[1];
  }
  bar();

  const int sw = (lr & 7) << 3;

  // ---- 13 pipelined phases, 1 barrier each ----
  for (int t = 0; t < 13; ++t) {
    const int buf = t & 1;

    // issue loads for tile t+2 (survive bar(); written next phase)
    float4 n0, n1;
    if (t < 11) {
      int gl = (t + 2) * 16 + srow;
      n0 = n1 = make_float4(0.f, 0.f, 0.f, 0.f);
      if (gl < 200) {
        const float4* kp4 = (const float4*)(keys + ((size_t)b * 200 + gl) * 128 + scol);
        n0 = kp4[0]; n1 = kp4[1];
      }
    }

    // ---- GEMM2 on tile t-1 (reads H1[buf^1]; independent of GEMM1 below) ----
    if (t >= 1) {
      const short* h1p = H1[buf ^ 1];
      f32x4 acc2[2];
#pragma unroll
      for (int nt2 = 0; nt2 < 2; ++nt2)
#pragma unroll
        for (int r = 0; r < 4; ++r) acc2[nt2][r] = b2l[wid * 32 + nt2 * 16 + lg * 4 + r];
      __builtin_amdgcn_s_setprio(1);
#pragma unroll
      for (int ks = 0; ks < 8; ++ks) {
        bf16x8 hf = *(const bf16x8*)(&h1p[lr * 256 + ((ks * 32 + lg * 8) ^ sw)]);
        acc2[0] = __builtin_amdgcn_mfma_f32_16x16x32_bf16(w2f[0][ks], hf, acc2[0], 0, 0, 0);
        acc2[1] = __builtin_amdgcn_mfma_f32_16x16x32_bf16(w2f[1][ks], hf, acc2[1], 0, 0, 0);
      }
      __builtin_amdgcn_s_setprio(0);
      float s = 0.f;
#pragma unroll
      for (int nt2 = 0; nt2 < 2; ++nt2)
#pragma unroll
        for (int r = 0; r < 4; ++r) {
          float v = acc2[nt2][r];
          v = (v >= 0.f) ? v : a2 * v;
          s += v * w3l[wid * 32 + nt2 * 16 + lg * 4 + r];
        }
      s += __shfl_xor(s, 16);
      s += __shfl_xor(s, 32);
      if (lg == 0) wred[wid][(t - 1) * 16 + lr] = s;
    }

    // ---- GEMM1 on tile t (reads Kt[buf], writes H1[buf]) ----
    {
      bf16x8 kf[4];
#pragma unroll
      for (int ks = 0; ks < 4; ++ks)
        kf[ks] = *(const bf16x8*)(&Kt[buf][lr * 128 + ((ks * 32 + lg * 8) ^ sw)]);
      f32x4 acc[4];
#pragma unroll
      for (int nt = 0; nt < 4; ++nt)
#pragma unroll
        for (int r = 0; r < 4; ++r) acc[nt][r] = Ul[wid * 64 + nt * 16 + lg * 4 + r];
      __builtin_amdgcn_s_setprio(1);
#pragma unroll
      for (int ks = 0; ks < 4; ++ks)
#pragma unroll
        for (int nt = 0; nt < 4; ++nt)
          acc[nt] = __builtin_amdgcn_mfma_f32_16x16x32_bf16(mf[nt][ks], kf[ks], acc[nt], 0, 0, 0);
      __builtin_amdgcn_s_setprio(0);
      short* h1b = H1[buf];
#pragma unroll
      for (int nt = 0; nt < 4; ++nt) {
        float v0 = acc[nt][0], v1 = acc[nt][1], v2 = acc[nt][2], v3 = acc[nt][3];
        v0 = (v0 >= 0.f) ? v0 : a1 * v0;
        v1 = (v1 >= 0.f) ? v1 : a1 * v1;
        v2 = (v2 >= 0.f) ? v2 : a1 * v2;
        v3 = (v3 >= 0.f) ? v3 : a1 * v3;
        union { bf16x4 v; uint32_t u[2]; } hh;
        hh.u[0] = pk2(v0, v1); hh.u[1] = pk2(v2, v3);
        int h0 = wid * 64 + nt * 16 + lg * 4;
        *(bf16x4*)(&h1b[lr * 256 + (h0 ^ sw)]) = hh.v;
      }
    }

    // ring write: tile t+1 -> Kt[buf^1]
    if (t < 12) {
      union { bf16x8 v; uint32_t u[4]; } w;
      w.u[0] = pk2(h0a.x, h0a.y); w.u[1] = pk2(h0a.z, h0a.w);
      w.u[2] = pk2(h0b.x, h0b.y); w.u[3] = pk2(h0b.z, h0b.w);
      *(bf16x8*)(&Kt[buf ^ 1][srow * 128 + (scol ^ ssw)]) = w.v;
    }
    if (t < 11) { h0a = n0; h0b = n1; }

    bar();  // the ONLY barrier per tile
  }

  // ---- drain: GEMM2 on tile 12 (H1[0]) ----
  {
    const short* h1p = H1[0];
    f32x4 acc2[2];
#pragma unroll
    for (int nt2 = 0; nt2 < 2; ++nt2)
#pragma unroll
      for (int r = 0; r < 4; ++r) acc2[nt2][r] = b2l[wid * 32 + nt2 * 16 + lg * 4 + r];
#pragma unroll
    for (int ks = 0; ks < 8; ++ks) {
      bf16x8 hf = *(const bf16x8*)(&h1p[lr * 256 + ((ks * 32 + lg * 8) ^ sw)]);
      acc2[0] = __builtin_amdgcn_mfma_f32_16x16x32_bf16(w2f[0][ks], hf, acc2[0], 0, 0, 0);
      acc2[1] = __builtin_amdgcn_mfma_f32_16x16x32_bf16(w2f[1][ks], hf, acc2[1], 0, 0, 0);
    }
    float s = 0.f;
#pragma unroll
    for (int nt2 = 0; nt2 < 2; ++nt2)
#pragma unroll
      for (int r = 0; r < 4; ++r) {
        float v = acc2[nt2][r];
        v = (v >= 0.f) ? v : a2 * v;
        s += v * w3l[wid * 32 + nt2 * 16 + lg * 4 + r];
      }
    s += __shfl_xor(s, 16);
    s += __shfl_xor(s, 32);
    if (lg == 0) wred[wid][12 * 16 + lr] = s;
  }
  bar();

  // ---- masked softmax over l=0..199 ----
  float val = NEGV;
  int mk = 0;
  if (tid < 200) {
    mk = mask[(size_t)b * 200 + tid];
    float sc = wred[0][tid] + wred[1][tid] + wred[2][tid] + wred[3][tid];
    val = mk ? sc : NEGV;
  }
  float m = val;
#pragma unroll
  for (int off = 1; off < 64; off <<= 1) m = fmaxf(m, __shfl_xor(m, off));
  if (lane == 0) red[wid] = m;
  bar();
  float smax = fmaxf(fmaxf(red[0], red[1]), fmaxf(red[2], red[3]));
  float pex = (tid < 200 && mk) ? __expf(val - smax) : 0.f;
  float s = pex;
#pragma unroll
  for (int off = 1; off < 64; off <<= 1) s += __shfl_xor(s, off);
  if (lane == 0) red[4 + wid] = s;
  bar();
  float ssum = red[4] + red[5] + red[6] + red[7];
  float winv = (ssum > 0.f) ? 1.f / ssum : 0.f;
  if (tid < 208) wl[tid] = (tid < 200) ? pex * winv : 0.f;
  bar();

  // ---- weighted sum from global keys (L3-hot) ----
  {
    const int d4 = (tid & 31) << 2;  // 0..124
    const int slice = tid >> 5;      // 0..7
    float ax = 0.f, ay = 0.f, az = 0.f, aw = 0.f;
    for (int l = slice; l < 200; l += 8) {
      float wv = wl[l];
      float4 kv = *(const float4*)(keys + ((size_t)b * 200 + l) * 128 + d4);
      ax += wv * kv.x; ay += wv * kv.y; az += wv * kv.z; aw += wv * kv.w;
    }
    *(float4*)(&opart[slice][d4]) = make_float4(ax, ay, az, aw);
  }
  __syncthreads();
  if (tid < 128) {
    float acc = 0.f;
#pragma unroll
    for (int i = 0; i < 8; ++i) acc += opart[i][tid];
    out[(size_t)b * 128 + tid] = acc;
  }
}

extern "C" void kernel_launch(void* const* d_in, const int* in_sizes, int n_in,
                              void* d_out, int out_size, void* d_ws, size_t ws_size,
                              hipStream_t stream) {
  const float* query = (const float*)d_in[0];
  const float* keys  = (const float*)d_in[1];
  const int*   maskp = (const int*)d_in[2];
  const float* W1    = (const float*)d_in[3];
  const float* b1    = (const float*)d_in[4];
  const float* a1    = (const float*)d_in[5];
  const float* W2    = (const float*)d_in[6];
  const float* b2    = (const float*)d_in[7];
  const float* a2    = (const float*)d_in[8];
  const float* W3    = (const float*)d_in[9];
  float* out = (float*)d_out;

  float* U   = (float*)d_ws;                         // 2 MiB
  short* Wk  = (short*)((char*)d_ws + 2097152);      // 64 KiB
  short* Wd  = Wk + 32768;                           // 64 KiB
  short* W2b = Wd + 32768;                           // 64 KiB

  prep_all<<<640, 256, 0, stream>>>(query, W1, W2, b1, Wk, Wd, W2b, U);
  din_fused<<<2048, 256, 0, stream>>>(query, keys, maskp, b2, a1, a2, W3,
                                      U, Wk, Wd, W2b, out);
}